// Round 3
// baseline (821.416 us; speedup 1.0000x reference)
//
#include <hip/hip_runtime.h>
#include <hip/hip_bf16.h>
#include <stdint.h>

#define Bn 32
#define Tn 2048
#define Hn 1024
#define Cn 1024

typedef short short8 __attribute__((ext_vector_type(8)));
typedef float floatx4 __attribute__((ext_vector_type(4)));

__device__ __forceinline__ unsigned int bf16_rne(float f) {
    union { float f; unsigned int u; } v; v.f = f;
    unsigned int u = v.u;
    return (u + 0x7fffu + ((u >> 16) & 1u)) >> 16;
}

__device__ __forceinline__ unsigned int pk_bf16(float a, float b) {
    return bf16_rne(a) | (bf16_rne(b) << 16);
}

// Async global->LDS, 16B per lane, wave-uniform LDS base.
__device__ __forceinline__ void load_lds_16(const float* g, float* l) {
    __builtin_amdgcn_global_load_lds(
        (const __attribute__((address_space(1))) unsigned int*)g,
        (__attribute__((address_space(3))) unsigned int*)l,
        16, 0, 0);
}

// dbias[b][c] = sum_h dec[b][h]*W[h][c]  (+ bias[c] once)
// grid (32, 4, 4) x 256 threads; dbias must be zeroed first.
__global__ void k_dbias(const float* __restrict__ dec, const float* __restrict__ W,
                        const float* __restrict__ bias, float* __restrict__ dbias) {
    const int b  = blockIdx.x;
    const int c  = blockIdx.y * 256 + threadIdx.x;
    const int h0 = blockIdx.z * 256;
    const float* dv = dec + b * Hn + h0;
    const float* wp = W + (size_t)h0 * Cn + c;
    float acc = 0.f;
#pragma unroll 8
    for (int h = 0; h < 256; ++h)
        acc += dv[h] * wp[(size_t)h * Cn];
    if (blockIdx.z == 0) acc += bias[c];
    atomicAdd(&dbias[b * Cn + c], acc);
}

// Pack V[k][c] fp32 -> bf16 in MFMA B-fragment order:
// vp[(nt*32 + kt)*64 + lane] holds 8 bf16: V[kt*32 + (lane>>4)*8 + j][nt*16 + (lane&15)]
__global__ void k_vpack(const float* __restrict__ V, uint4* __restrict__ vp) {
    const int bid  = blockIdx.x;
    const int nt   = bid >> 5;
    const int kt   = bid & 31;
    const int lane = threadIdx.x;
    const int c    = nt * 16 + (lane & 15);
    const int k0   = kt * 32 + (lane >> 4) * 8;
    unsigned int h[8];
#pragma unroll
    for (int j = 0; j < 8; ++j)
        h[j] = bf16_rne(V[(size_t)(k0 + j) * Cn + c]);
    uint4 u;
    u.x = h[0] | (h[1] << 16);
    u.y = h[2] | (h[3] << 16);
    u.z = h[4] | (h[5] << 16);
    u.w = h[6] | (h[7] << 16);
    vp[(size_t)bid * 64 + lane] = u;
}

#define BLK_M 64
#define KC    256      // K-chunk (floats)
#define NCH   4        // 1024 / 256
#define LDAF  260      // 256 + 4 pad floats; row stride 1040B

struct ScoresShared {
    float A[2][BLK_M][LDAF];   // 133,120 B fp32 double-buffered A chunk
    float scores[BLK_M];
};

// Fused enc_proj GEMM + tanh + dot(w) -> scores[B*T]
// grid 1024 x 512 threads (8 waves). Block = 64 rows x 1024 cols; wave w owns
// col slices w*64 (ni=0) and (w+8)*64 (ni=1); acc for both resident (128 AGPR).
__global__ __launch_bounds__(512, 2)
void k_scores(const float* __restrict__ enc, const uint4* __restrict__ vp,
              const float* __restrict__ dbias, const float* __restrict__ wv,
              float* __restrict__ scores_g) {
    __shared__ ScoresShared sh;
    const int tid  = threadIdx.x;
    const int lane = tid & 63;
    const int wid  = tid >> 6;
    const int wg   = blockIdx.x;
    const int b    = wg >> 5;
    const int row0 = wg * BLK_M;
    const int lhi  = lane >> 4;
    const int llo  = lane & 15;

    if (tid < BLK_M) sh.scores[tid] = 0.f;

    const float* grow = enc + (size_t)row0 * Hn + lane * 4;  // per-lane 16B slot

    // Prologue: stage chunk 0 into buffer 0 (8 rows per wave, 1 row = 1 instr).
#pragma unroll
    for (int i = 0; i < 8; ++i) {
        const int r = wid * 8 + i;
        load_lds_16(grow + (size_t)r * Hn, &sh.A[0][r][0]);
    }
    __syncthreads();

    const int nt0 = wid * 4;          // ni=0: cols wid*64
    const int nt1 = (wid + 8) * 4;    // ni=1: cols (wid+8)*64

    floatx4 acc[2][4][4];
#pragma unroll
    for (int n = 0; n < 2; ++n)
#pragma unroll
        for (int i = 0; i < 4; ++i)
#pragma unroll
            for (int j = 0; j < 4; ++j)
                acc[n][i][j] = (floatx4){0.f, 0.f, 0.f, 0.f};

    for (int c = 0; c < NCH; ++c) {
        const int cb = c & 1;
        const int kbase = c * 8;

        // preload B fragments for kt=0
        uint4 bcur[8];
#pragma unroll
        for (int j = 0; j < 4; ++j) {
            bcur[j]     = vp[((nt0 + j) * 32 + kbase) * 64 + lane];
            bcur[4 + j] = vp[((nt1 + j) * 32 + kbase) * 64 + lane];
        }

#pragma unroll
        for (int kt = 0; kt < 8; ++kt) {
            // depth-1 prefetch of next kt's B fragments (issued first)
            uint4 bnxt[8];
            if (kt < 7) {
                const int kg = kbase + kt + 1;
#pragma unroll
                for (int j = 0; j < 4; ++j) {
                    bnxt[j]     = vp[((nt0 + j) * 32 + kg) * 64 + lane];
                    bnxt[4 + j] = vp[((nt1 + j) * 32 + kg) * 64 + lane];
                }
            }
            // async staging of chunk c+1, 2 rows/iter over kt=0..3
            if (c < NCH - 1 && kt < 4) {
                const int r0 = wid * 8 + kt * 2;
                const float* gsrc = grow + (size_t)(c + 1) * KC;
                load_lds_16(gsrc + (size_t)r0 * Hn,       &sh.A[cb ^ 1][r0][0]);
                load_lds_16(gsrc + (size_t)(r0 + 1) * Hn, &sh.A[cb ^ 1][r0 + 1][0]);
            }

            // A fragments from fp32 LDS, cvt->bf16 in-register (shared by both ni)
            short8 afr[4];
#pragma unroll
            for (int rg = 0; rg < 4; ++rg) {
                const float* ap = &sh.A[cb][rg * 16 + llo][kt * 32 + lhi * 8];
                float4 f0 = *(const float4*)ap;
                float4 f1 = *(const float4*)(ap + 4);
                uint4 u;
                u.x = pk_bf16(f0.x, f0.y);
                u.y = pk_bf16(f0.z, f0.w);
                u.z = pk_bf16(f1.x, f1.y);
                u.w = pk_bf16(f1.z, f1.w);
                afr[rg] = __builtin_bit_cast(short8, u);
            }

#pragma unroll
            for (int rg = 0; rg < 4; ++rg)
#pragma unroll
                for (int j = 0; j < 4; ++j) {
                    acc[0][rg][j] = __builtin_amdgcn_mfma_f32_16x16x32_bf16(
                        afr[rg], __builtin_bit_cast(short8, bcur[j]), acc[0][rg][j], 0, 0, 0);
                    acc[1][rg][j] = __builtin_amdgcn_mfma_f32_16x16x32_bf16(
                        afr[rg], __builtin_bit_cast(short8, bcur[4 + j]), acc[1][rg][j], 0, 0, 0);
                }

            if (kt < 7) {
#pragma unroll
                for (int j = 0; j < 8; ++j) bcur[j] = bnxt[j];
            }
        }
        __syncthreads();
    }

    // Epilogue: score_part[rg*4+r] += tanh(acc + dbias[c]) * w[c]
    float score_part[16];
#pragma unroll
    for (int i = 0; i < 16; ++i) score_part[i] = 0.f;

#pragma unroll
    for (int ni = 0; ni < 2; ++ni) {
        const int colbase = (ni * 8 + wid) * 64;
#pragma unroll
        for (int j = 0; j < 4; ++j) {
            const int cc   = colbase + j * 16 + llo;
            const float db = dbias[b * Cn + cc];
            const float wc = wv[cc];
#pragma unroll
            for (int rg = 0; rg < 4; ++rg) {
#pragma unroll
                for (int r = 0; r < 4; ++r) {
                    float x = acc[ni][rg][j][r] + db;
                    x = fminf(fmaxf(x, -12.f), 12.f);
                    float e = __expf(2.f * x);
                    float t = 1.f - 2.f / (e + 1.f);
                    score_part[rg * 4 + r] += t * wc;
                }
            }
        }
    }

#pragma unroll
    for (int i = 0; i < 16; ++i) {
        float v = score_part[i];
        v += __shfl_xor(v, 1);
        v += __shfl_xor(v, 2);
        v += __shfl_xor(v, 4);
        v += __shfl_xor(v, 8);
        score_part[i] = v;
    }
    if (llo == 0) {
#pragma unroll
        for (int rg = 0; rg < 4; ++rg)
#pragma unroll
            for (int r = 0; r < 4; ++r)
                atomicAdd(&sh.scores[rg * 16 + lhi * 4 + r], score_part[rg * 4 + r]);
    }
    __syncthreads();
    if (tid < BLK_M) scores_g[row0 + tid] = sh.scores[tid];
}

// Softmax over T per batch. grid 32 x 256.
__global__ void k_softmax(const float* __restrict__ scores, float* __restrict__ align) {
    const int b   = blockIdx.x;
    const int tid = threadIdx.x;
    const float* s = scores + b * Tn;
    float v[8];
    float lmax = -1e30f;
#pragma unroll
    for (int i = 0; i < 8; ++i) { v[i] = s[tid + i * 256]; lmax = fmaxf(lmax, v[i]); }
    for (int off = 1; off < 64; off <<= 1) lmax = fmaxf(lmax, __shfl_xor(lmax, off));
    __shared__ float red[4];
    __shared__ float red2[4];
    if ((tid & 63) == 0) red[tid >> 6] = lmax;
    __syncthreads();
    lmax = fmaxf(fmaxf(red[0], red[1]), fmaxf(red[2], red[3]));
    float lsum = 0.f;
#pragma unroll
    for (int i = 0; i < 8; ++i) { v[i] = __expf(v[i] - lmax); lsum += v[i]; }
    for (int off = 1; off < 64; off <<= 1) lsum += __shfl_xor(lsum, off);
    if ((tid & 63) == 0) red2[tid >> 6] = lsum;
    __syncthreads();
    lsum = red2[0] + red2[1] + red2[2] + red2[3];
    const float inv = 1.f / lsum;
#pragma unroll
    for (int i = 0; i < 8; ++i) align[b * Tn + tid + i * 256] = v[i] * inv;
}

// Partial context: part[(tc*32 + b)*1024 + h] = sum over 64 t of align*enc.
// grid (32 b, 32 tc) x 256 threads; 4 independent FMA chains per thread.
__global__ void k_ctx_part(const float* __restrict__ enc, const float* __restrict__ align,
                           float* __restrict__ part) {
    const int b   = blockIdx.x;
    const int tc  = blockIdx.y;
    const int tid = threadIdx.x;
    const floatx4* ep = (const floatx4*)(enc + ((size_t)b * Tn + tc * 64) * Hn);
    const float*   al = align + b * Tn + tc * 64;
    floatx4 a0 = {0.f,0.f,0.f,0.f}, a1 = a0, a2 = a0, a3 = a0;
    for (int t = 0; t < 64; t += 4) {
        const float w0 = al[t], w1 = al[t+1], w2 = al[t+2], w3 = al[t+3];
        a0 += w0 * ep[(t+0) * 256 + tid];
        a1 += w1 * ep[(t+1) * 256 + tid];
        a2 += w2 * ep[(t+2) * 256 + tid];
        a3 += w3 * ep[(t+3) * 256 + tid];
    }
    ((floatx4*)part)[(tc * Bn + b) * 256 + tid] = (a0 + a1) + (a2 + a3);
}

// Reduce partials over tc. grid 32 x 256; idx covers 8192 float4 of [b][h].
__global__ void k_ctx_red(const float* __restrict__ part, float* __restrict__ out) {
    const int idx = blockIdx.x * 256 + threadIdx.x;
    const floatx4* p = (const floatx4*)part;
    floatx4 s = {0.f,0.f,0.f,0.f};
#pragma unroll
    for (int tc = 0; tc < 32; ++tc)
        s += p[tc * 8192 + idx];
    ((floatx4*)out)[idx] = s;
}

extern "C" void kernel_launch(void* const* d_in, const int* in_sizes, int n_in,
                              void* d_out, int out_size, void* d_ws, size_t ws_size,
                              hipStream_t stream) {
    const float* dec  = (const float*)d_in[0];   // [32,1,1024]
    const float* enc  = (const float*)d_in[1];   // [32,2048,1024]
    const float* W    = (const float*)d_in[2];   // [1024,1024]
    const float* V    = (const float*)d_in[3];   // [1024,1024]
    const float* bias = (const float*)d_in[4];   // [1024]
    const float* wv   = (const float*)d_in[5];   // [1024,1]
    float* out = (float*)d_out;                  // [32,1024]

    char* ws = (char*)d_ws;
    float* dbias  = (float*)(ws);                              // 128 KB
    uint4* vpack  = (uint4*)(ws + 131072);                     // 2 MB
    float* scores = (float*)(ws + 131072 + 2097152);           // 256 KB
    float* align  = (float*)(ws + 2490368);                    // 256 KB
    float* cpart  = (float*)(ws + 2752512);                    // 4 MB

    (void)hipMemsetAsync(dbias, 0, 131072, stream);

    k_dbias   <<<dim3(32, 4, 4), 256, 0, stream>>>(dec, W, bias, dbias);
    k_vpack   <<<2048, 64, 0, stream>>>(V, vpack);
    k_scores  <<<1024, 512, 0, stream>>>(enc, vpack, dbias, wv, scores);
    k_softmax <<<32, 256, 0, stream>>>(scores, align);
    k_ctx_part<<<dim3(32, 32), 256, 0, stream>>>(enc, align, cpart);
    k_ctx_red <<<32, 256, 0, stream>>>(cpart, out);
}

// Round 4
// 586.192 us; speedup vs baseline: 1.4013x; 1.4013x over previous
//
#include <hip/hip_runtime.h>
#include <hip/hip_bf16.h>
#include <stdint.h>

#define Bn 32
#define Tn 2048
#define Hn 1024
#define Cn 1024

typedef short short8 __attribute__((ext_vector_type(8)));
typedef float floatx4 __attribute__((ext_vector_type(4)));

__device__ __forceinline__ unsigned int bf16_rne(float f) {
    union { float f; unsigned int u; } v; v.f = f;
    unsigned int u = v.u;
    return (u + 0x7fffu + ((u >> 16) & 1u)) >> 16;
}

__device__ __forceinline__ unsigned int pk_bf16(float a, float b) {
    return bf16_rne(a) | (bf16_rne(b) << 16);
}

// dbias[b][c] = sum_h dec[b][h]*W[h][c]  (+ bias[c] once)
__global__ void k_dbias(const float* __restrict__ dec, const float* __restrict__ W,
                        const float* __restrict__ bias, float* __restrict__ dbias) {
    const int b  = blockIdx.x;
    const int c  = blockIdx.y * 256 + threadIdx.x;
    const int h0 = blockIdx.z * 256;
    const float* dv = dec + b * Hn + h0;
    const float* wp = W + (size_t)h0 * Cn + c;
    float acc = 0.f;
#pragma unroll 8
    for (int h = 0; h < 256; ++h)
        acc += dv[h] * wp[(size_t)h * Cn];
    if (blockIdx.z == 0) acc += bias[c];
    atomicAdd(&dbias[b * Cn + c], acc);
}

// Pack V[k][c] fp32 -> bf16 in MFMA B-fragment order (verified R1 layout):
// vp[(nt*32 + kt)*64 + lane]: V[kt*32 + (lane>>4)*8 + j][nt*16 + (lane&15)]
__global__ void k_vpack(const float* __restrict__ V, uint4* __restrict__ vp) {
    const int bid  = blockIdx.x;
    const int nt   = bid >> 5;
    const int kt   = bid & 31;
    const int lane = threadIdx.x;
    const int c    = nt * 16 + (lane & 15);
    const int k0   = kt * 32 + (lane >> 4) * 8;
    unsigned int h[8];
#pragma unroll
    for (int j = 0; j < 8; ++j)
        h[j] = bf16_rne(V[(size_t)(k0 + j) * Cn + c]);
    uint4 u;
    u.x = h[0] | (h[1] << 16);
    u.y = h[2] | (h[3] << 16);
    u.z = h[4] | (h[5] << 16);
    u.w = h[6] | (h[7] << 16);
    vp[(size_t)bid * 64 + lane] = u;
}

#define BLK_M 64

// A in LDS, fragment-major: slot s = (ktg*4 + rg)*64 + lane holds 16B =
// 8 bf16 of A[row0 + rg*16 + (lane&15)][ktg*32 + (lane>>4)*8 + 0..7].
struct ScoresShared {
    uint4 A[32 * 4 * 64];   // 131072 B
    float scores[BLK_M];
};

// Fused enc_proj GEMM + tanh + dot(w) -> scores[B*T].
// grid 1024 x 512 (8 waves). Pass 0 (cols wid*64) is fused with K-chunked
// staging (4 chunks of 256, 1 barrier each); pass 1 (cols (wid+8)*64) is
// barrier-free. Only one acc[4][4] resident at a time.
__global__ __launch_bounds__(512, 2)
void k_scores(const float* __restrict__ enc, const uint4* __restrict__ vp,
              const float* __restrict__ dbias, const float* __restrict__ wv,
              float* __restrict__ scores_g) {
    __shared__ ScoresShared sh;
    const int tid  = threadIdx.x;
    const int lane = tid & 63;
    const int wid  = tid >> 6;
    const int wg   = blockIdx.x;
    const int b    = wg >> 5;
    const int row0 = wg * BLK_M;
    const int lhi  = lane >> 4;
    const int llo  = lane & 15;

    if (tid < BLK_M) sh.scores[tid] = 0.f;

    // Staging decode: chunk-local frag id f = i*512 + tid,
    // m=f&15, kgrp=(f>>4)&3, rg=(f>>6)&3, ktl=(f>>8)&7.
    // Global float4 index: (row0+rg*16+m)*256 + c*64 + ktl*8 + kgrp*2 (+0,+1).
    const float4* encf4 = (const float4*)enc;
    int g_off[4];
#pragma unroll
    for (int i = 0; i < 4; ++i) {
        const int f = i * 512 + tid;
        const int m = f & 15, kgrp = (f >> 4) & 3, rg = (f >> 6) & 3, ktl = (f >> 8) & 7;
        g_off[i] = (row0 + rg * 16 + m) * 256 + ktl * 8 + kgrp * 2;
    }

    float4 st[8];
    // Prologue: load + write chunk 0.
#pragma unroll
    for (int i = 0; i < 4; ++i) {
        const float4* g = &encf4[g_off[i]];
        st[2 * i]     = g[0];
        st[2 * i + 1] = g[1];
    }
#pragma unroll
    for (int i = 0; i < 4; ++i) {
        uint4 u;
        u.x = pk_bf16(st[2*i].x,   st[2*i].y);
        u.y = pk_bf16(st[2*i].z,   st[2*i].w);
        u.z = pk_bf16(st[2*i+1].x, st[2*i+1].y);
        u.w = pk_bf16(st[2*i+1].z, st[2*i+1].w);
        sh.A[i * 512 + tid] = u;
    }
    __syncthreads();

    float score_part[16];
#pragma unroll
    for (int i = 0; i < 16; ++i) score_part[i] = 0.f;

    floatx4 acc[4][4];
    uint4 bcur[4], bnxt[4];

    // ---------------- Pass 0 (cols wid*64), fused with staging ----------------
    const int nt0 = wid * 4;
#pragma unroll
    for (int rg = 0; rg < 4; ++rg)
#pragma unroll
        for (int j = 0; j < 4; ++j)
            acc[rg][j] = (floatx4){0.f, 0.f, 0.f, 0.f};
#pragma unroll
    for (int j = 0; j < 4; ++j)
        bcur[j] = vp[((nt0 + j) * 32 + 0) * 64 + lane];

    for (int c = 0; c < 4; ++c) {
        if (c < 3) {
#pragma unroll
            for (int i = 0; i < 4; ++i) {
                const float4* g = &encf4[g_off[i] + (c + 1) * 64];
                st[2 * i]     = g[0];
                st[2 * i + 1] = g[1];
            }
        }
#pragma unroll
        for (int ktl = 0; ktl < 8; ++ktl) {
            const int ktg = c * 8 + ktl;
            if (ktg < 31) {
#pragma unroll
                for (int j = 0; j < 4; ++j)
                    bnxt[j] = vp[((nt0 + j) * 32 + ktg + 1) * 64 + lane];
            }
            short8 afr[4];
#pragma unroll
            for (int rg = 0; rg < 4; ++rg)
                afr[rg] = __builtin_bit_cast(short8, sh.A[(ktg * 4 + rg) * 64 + lane]);
#pragma unroll
            for (int rg = 0; rg < 4; ++rg)
#pragma unroll
                for (int j = 0; j < 4; ++j)
                    acc[rg][j] = __builtin_amdgcn_mfma_f32_16x16x32_bf16(
                        afr[rg], __builtin_bit_cast(short8, bcur[j]), acc[rg][j], 0, 0, 0);
            if (ktg < 31) {
#pragma unroll
                for (int j = 0; j < 4; ++j) bcur[j] = bnxt[j];
            }
        }
        if (c < 3) {
#pragma unroll
            for (int i = 0; i < 4; ++i) {
                uint4 u;
                u.x = pk_bf16(st[2*i].x,   st[2*i].y);
                u.y = pk_bf16(st[2*i].z,   st[2*i].w);
                u.z = pk_bf16(st[2*i+1].x, st[2*i+1].y);
                u.w = pk_bf16(st[2*i+1].z, st[2*i+1].w);
                sh.A[(c + 1) * 2048 + i * 512 + tid] = u;
            }
            __syncthreads();
        }
    }
    // Fold pass 0.
    {
        const int colbase = wid * 64;
#pragma unroll
        for (int j = 0; j < 4; ++j) {
            const int cc   = colbase + j * 16 + llo;
            const float db = dbias[b * Cn + cc];
            const float wc = wv[cc];
#pragma unroll
            for (int rg = 0; rg < 4; ++rg)
#pragma unroll
                for (int r = 0; r < 4; ++r) {
                    float x = acc[rg][j][r] + db;
                    x = fminf(fmaxf(x, -12.f), 12.f);
                    float e = __expf(2.f * x);
                    float t = 1.f - 2.f / (e + 1.f);
                    score_part[rg * 4 + r] += t * wc;
                }
        }
    }

    // ---------------- Pass 1 (cols (wid+8)*64), barrier-free ----------------
    const int nt1 = (wid + 8) * 4;
#pragma unroll
    for (int rg = 0; rg < 4; ++rg)
#pragma unroll
        for (int j = 0; j < 4; ++j)
            acc[rg][j] = (floatx4){0.f, 0.f, 0.f, 0.f};
#pragma unroll
    for (int j = 0; j < 4; ++j)
        bcur[j] = vp[((nt1 + j) * 32 + 0) * 64 + lane];

#pragma unroll 4
    for (int ktg = 0; ktg < 32; ++ktg) {
        if (ktg < 31) {
#pragma unroll
            for (int j = 0; j < 4; ++j)
                bnxt[j] = vp[((nt1 + j) * 32 + ktg + 1) * 64 + lane];
        }
        short8 afr[4];
#pragma unroll
        for (int rg = 0; rg < 4; ++rg)
            afr[rg] = __builtin_bit_cast(short8, sh.A[(ktg * 4 + rg) * 64 + lane]);
#pragma unroll
        for (int rg = 0; rg < 4; ++rg)
#pragma unroll
            for (int j = 0; j < 4; ++j)
                acc[rg][j] = __builtin_amdgcn_mfma_f32_16x16x32_bf16(
                    afr[rg], __builtin_bit_cast(short8, bcur[j]), acc[rg][j], 0, 0, 0);
        if (ktg < 31) {
#pragma unroll
            for (int j = 0; j < 4; ++j) bcur[j] = bnxt[j];
        }
    }
    // Fold pass 1.
    {
        const int colbase = (wid + 8) * 64;
#pragma unroll
        for (int j = 0; j < 4; ++j) {
            const int cc   = colbase + j * 16 + llo;
            const float db = dbias[b * Cn + cc];
            const float wc = wv[cc];
#pragma unroll
            for (int rg = 0; rg < 4; ++rg)
#pragma unroll
                for (int r = 0; r < 4; ++r) {
                    float x = acc[rg][j][r] + db;
                    x = fminf(fmaxf(x, -12.f), 12.f);
                    float e = __expf(2.f * x);
                    float t = 1.f - 2.f / (e + 1.f);
                    score_part[rg * 4 + r] += t * wc;
                }
        }
    }

    // Reduce over the 16 lanes (llo) sharing each row, then across waves.
#pragma unroll
    for (int i = 0; i < 16; ++i) {
        float v = score_part[i];
        v += __shfl_xor(v, 1);
        v += __shfl_xor(v, 2);
        v += __shfl_xor(v, 4);
        v += __shfl_xor(v, 8);
        score_part[i] = v;
    }
    if (llo == 0) {
#pragma unroll
        for (int rg = 0; rg < 4; ++rg)
#pragma unroll
            for (int r = 0; r < 4; ++r)
                atomicAdd(&sh.scores[rg * 16 + lhi * 4 + r], score_part[rg * 4 + r]);
    }
    __syncthreads();
    if (tid < BLK_M) scores_g[row0 + tid] = sh.scores[tid];
}

// Softmax over T per batch. grid 32 x 256.
__global__ void k_softmax(const float* __restrict__ scores, float* __restrict__ align) {
    const int b   = blockIdx.x;
    const int tid = threadIdx.x;
    const float* s = scores + b * Tn;
    float v[8];
    float lmax = -1e30f;
#pragma unroll
    for (int i = 0; i < 8; ++i) { v[i] = s[tid + i * 256]; lmax = fmaxf(lmax, v[i]); }
    for (int off = 1; off < 64; off <<= 1) lmax = fmaxf(lmax, __shfl_xor(lmax, off));
    __shared__ float red[4];
    __shared__ float red2[4];
    if ((tid & 63) == 0) red[tid >> 6] = lmax;
    __syncthreads();
    lmax = fmaxf(fmaxf(red[0], red[1]), fmaxf(red[2], red[3]));
    float lsum = 0.f;
#pragma unroll
    for (int i = 0; i < 8; ++i) { v[i] = __expf(v[i] - lmax); lsum += v[i]; }
    for (int off = 1; off < 64; off <<= 1) lsum += __shfl_xor(lsum, off);
    if ((tid & 63) == 0) red2[tid >> 6] = lsum;
    __syncthreads();
    lsum = red2[0] + red2[1] + red2[2] + red2[3];
    const float inv = 1.f / lsum;
#pragma unroll
    for (int i = 0; i < 8; ++i) align[b * Tn + tid + i * 256] = v[i] * inv;
}

// Partial context over 64-t chunks. grid (32, 32) x 256.
__global__ void k_ctx_part(const float* __restrict__ enc, const float* __restrict__ align,
                           float* __restrict__ part) {
    const int b   = blockIdx.x;
    const int tc  = blockIdx.y;
    const int tid = threadIdx.x;
    const floatx4* ep = (const floatx4*)(enc + ((size_t)b * Tn + tc * 64) * Hn);
    const float*   al = align + b * Tn + tc * 64;
    floatx4 a0 = {0.f,0.f,0.f,0.f}, a1 = a0, a2 = a0, a3 = a0;
    for (int t = 0; t < 64; t += 4) {
        const float w0 = al[t], w1 = al[t+1], w2 = al[t+2], w3 = al[t+3];
        a0 += w0 * ep[(t+0) * 256 + tid];
        a1 += w1 * ep[(t+1) * 256 + tid];
        a2 += w2 * ep[(t+2) * 256 + tid];
        a3 += w3 * ep[(t+3) * 256 + tid];
    }
    ((floatx4*)part)[(tc * Bn + b) * 256 + tid] = (a0 + a1) + (a2 + a3);
}

// Reduce partials over tc. grid 32 x 256.
__global__ void k_ctx_red(const float* __restrict__ part, float* __restrict__ out) {
    const int idx = blockIdx.x * 256 + threadIdx.x;
    const floatx4* p = (const floatx4*)part;
    floatx4 s = {0.f,0.f,0.f,0.f};
#pragma unroll
    for (int tc = 0; tc < 32; ++tc)
        s += p[tc * 8192 + idx];
    ((floatx4*)out)[idx] = s;
}

extern "C" void kernel_launch(void* const* d_in, const int* in_sizes, int n_in,
                              void* d_out, int out_size, void* d_ws, size_t ws_size,
                              hipStream_t stream) {
    const float* dec  = (const float*)d_in[0];   // [32,1,1024]
    const float* enc  = (const float*)d_in[1];   // [32,2048,1024]
    const float* W    = (const float*)d_in[2];   // [1024,1024]
    const float* V    = (const float*)d_in[3];   // [1024,1024]
    const float* bias = (const float*)d_in[4];   // [1024]
    const float* wv   = (const float*)d_in[5];   // [1024,1]
    float* out = (float*)d_out;                  // [32,1024]

    char* ws = (char*)d_ws;
    float* dbias  = (float*)(ws);                              // 128 KB
    uint4* vpack  = (uint4*)(ws + 131072);                     // 2 MB
    float* scores = (float*)(ws + 131072 + 2097152);           // 256 KB
    float* align  = (float*)(ws + 2490368);                    // 256 KB
    float* cpart  = (float*)(ws + 2752512);                    // 4 MB

    (void)hipMemsetAsync(dbias, 0, 131072, stream);

    k_dbias   <<<dim3(32, 4, 4), 256, 0, stream>>>(dec, W, bias, dbias);
    k_vpack   <<<2048, 64, 0, stream>>>(V, vpack);
    k_scores  <<<1024, 512, 0, stream>>>(enc, vpack, dbias, wv, scores);
    k_softmax <<<32, 256, 0, stream>>>(scores, align);
    k_ctx_part<<<dim3(32, 32), 256, 0, stream>>>(enc, align, cpart);
    k_ctx_red <<<32, 256, 0, stream>>>(cpart, out);
}